// Round 6
// baseline (208.895 us; speedup 1.0000x reference)
//
#include <hip/hip_runtime.h>

typedef __bf16 bf16_t;
typedef bf16_t bf16x8 __attribute__((ext_vector_type(8)));
typedef float  f32x4  __attribute__((ext_vector_type(4)));
typedef unsigned int u32;
typedef u32    u32x4  __attribute__((ext_vector_type(4)));
typedef unsigned short u16;

#define B_SZ   4
#define N_SZ   4608
#define C_SZ   64
#define KVB    32
#define QROWS  32
#define NKVT   (N_SZ / KVB)     // 144
#define NQT    (N_SZ / QROWS)   // 144
#define WV     4                // waves per attn block (split-KV)
#define TPW    (NKVT / WV)      // 36 tiles per wave

__device__ __forceinline__ f32x4 mfma16(bf16x8 a, bf16x8 b, f32x4 c) {
  return __builtin_amdgcn_mfma_f32_16x16x32_bf16(a, b, c, 0, 0, 0);
}

__device__ __forceinline__ u32 pk2(float a, float b) {
  u16 ua = __builtin_bit_cast(u16, (bf16_t)a);
  u16 ub = __builtin_bit_cast(u16, (bf16_t)b);
  return (u32)ua | ((u32)ub << 16);
}

// ---- pre-kernel: fp32 input -> khi/klo (bf16 hi/lo, row-major [b][n][c])
//                             -> vt (bf16, transposed [b][c][n])
__global__ __launch_bounds__(256) void transform_k(
    const float* __restrict__ in, bf16_t* __restrict__ khi,
    bf16_t* __restrict__ klo, bf16_t* __restrict__ vt) {
  __shared__ float tile[64 * 65];
  const int bid = blockIdx.x;            // 288 blocks: (b, 64-row chunk)
  const int b  = bid / 72;
  const int n0 = (bid - b * 72) * 64;
  const int t  = threadIdx.x;
  {
    const int nl = t >> 2, c0 = (t & 3) * 16;
    const float* src = in + ((size_t)(b * N_SZ + n0 + nl)) * C_SZ + c0;
    float v[16];
    *(float4*)(v +  0) = *(const float4*)(src +  0);
    *(float4*)(v +  4) = *(const float4*)(src +  4);
    *(float4*)(v +  8) = *(const float4*)(src +  8);
    *(float4*)(v + 12) = *(const float4*)(src + 12);
    bf16x8 h8[2], l8[2];
#pragma unroll
    for (int i = 0; i < 16; ++i) {
      bf16_t h = (bf16_t)v[i];
      h8[i >> 3][i & 7] = h;
      l8[i >> 3][i & 7] = (bf16_t)(v[i] - (float)h);
      tile[nl * 65 + c0 + i] = v[i];
    }
    bf16_t* dh = khi + ((size_t)(b * N_SZ + n0 + nl)) * C_SZ + c0;
    bf16_t* dl = klo + ((size_t)(b * N_SZ + n0 + nl)) * C_SZ + c0;
    *(bf16x8*)(dh) = h8[0]; *(bf16x8*)(dh + 8) = h8[1];
    *(bf16x8*)(dl) = l8[0]; *(bf16x8*)(dl + 8) = l8[1];
  }
  __syncthreads();
  {
    const int c = t >> 2, m0 = (t & 3) * 16;
    bf16x8 o[2];
#pragma unroll
    for (int i = 0; i < 16; ++i)
      o[i >> 3][i & 7] = (bf16_t)tile[(m0 + i) * 65 + c];
    bf16_t* dst = vt + ((size_t)(b * C_SZ + c)) * N_SZ + n0 + m0;
    *(bf16x8*)(dst) = o[0]; *(bf16x8*)(dst + 8) = o[1];
  }
}

// load one KV tile's fragments (12 x dwordx4 global loads)
#define LOAD_TILE(KV0, KH, KL, VF)                                             \
  {                                                                            \
    _Pragma("unroll")                                                          \
    for (int ct = 0; ct < 2; ++ct)                                             \
      _Pragma("unroll")                                                        \
      for (int ks = 0; ks < 2; ++ks) {                                         \
        const size_t a = (size_t)((KV0) + ct * 16 + c15) * C_SZ + ks * 32 + g * 8; \
        KH[ct][ks] = *(const bf16x8*)(kh_b + a);                               \
        KL[ct][ks] = *(const bf16x8*)(kl_b + a);                               \
      }                                                                        \
    _Pragma("unroll")                                                          \
    for (int co = 0; co < 4; ++co)                                             \
      VF[co] = *(const bf16x8*)(vt_b + (size_t)(co * 16 + c15) * N_SZ + (KV0) + g * 8); \
  }

// ---- main attention: 576 blocks x 4 waves; split-KV, barrier-free hot loop
__global__ __launch_bounds__(256, 2) void attn_fwd(
    const float* __restrict__ in, const bf16_t* __restrict__ khi,
    const bf16_t* __restrict__ klo, const bf16_t* __restrict__ vt,
    const float* __restrict__ gamma_p, float* __restrict__ out) {
  __shared__ float obuf[256 * 36];            // per-wave O^T partials
  __shared__ float mlbuf[4 * 2 * 2 * 16];     // [w][j][{m,l}][q16]

  const int bid0 = blockIdx.x;
  const int bid  = (bid0 & 7) * 72 + (bid0 >> 3);  // XCD swizzle (576 % 8 == 0: bijective)
  const int b  = bid / NQT;
  const int qt = bid - b * NQT;
  const int t  = threadIdx.x;
  const int w  = t >> 6, l = t & 63;
  const int c15 = l & 15, g = l >> 4;

  const bf16_t* kh_b = khi + (size_t)b * N_SZ * C_SZ;
  const bf16_t* kl_b = klo + (size_t)b * N_SZ * C_SZ;
  const bf16_t* vt_b = vt  + (size_t)b * C_SZ * N_SZ;

  // Q fragments (B-operand of swapped QK^T): B[k=ch][col=q-row]
  bf16x8 qh[2][2], ql[2][2];
#pragma unroll
  for (int j = 0; j < 2; ++j)
#pragma unroll
    for (int ks = 0; ks < 2; ++ks) {
      const size_t a = (size_t)(qt * QROWS + j * 16 + c15) * C_SZ + ks * 32 + g * 8;
      qh[j][ks] = *(const bf16x8*)(kh_b + a);
      ql[j][ks] = *(const bf16x8*)(kl_b + a);
    }

  f32x4 acc[4][2];   // O^T tiles: [c-tile][q-tile]; reg r -> c = co*16+g*4+r, q = j*16+c15
#pragma unroll
  for (int co = 0; co < 4; ++co)
#pragma unroll
    for (int j = 0; j < 2; ++j)
      acc[co][j] = (f32x4){0.f, 0.f, 0.f, 0.f};
  float m_j[2] = {-3.0e38f, -3.0e38f}, l_j[2] = {0.f, 0.f};

  const int sA = ((l >> 4) & 1) * 32 + c15;   // P-relayout source lanes
  const int sB = sA + 16;
  const bool hi_half = (l >= 32);             // selects ct = g>>1

  // software pipeline: tile t+1 loads issue before tile t's compute consumes
  bf16x8 khf[2][2], klf[2][2], vf[4];
  LOAD_TILE(w * KVB, khf, klf, vf);

  for (int it = 0; it < TPW; ++it) {
    const int itn = (it + 1 < TPW) ? it + 1 : 0;     // wrap: dummy prefetch on last
    const int kvn = (w + itn * WV) * KVB;
    bf16x8 nkh[2][2], nkl[2][2], nvf[4];
    LOAD_TILE(kvn, nkh, nkl, nvf);

    // S^T = K·Q^T (3-term hi/lo): lane holds S[q=j*16+c15][kv=ct*16+g*4+r]
    f32x4 s[2][2];
#pragma unroll
    for (int j = 0; j < 2; ++j)
#pragma unroll
      for (int ct = 0; ct < 2; ++ct) {
        f32x4 a = (f32x4){0.f, 0.f, 0.f, 0.f};
#pragma unroll
        for (int ks = 0; ks < 2; ++ks) {
          a = mfma16(khf[ct][ks], qh[j][ks], a);
          a = mfma16(khf[ct][ks], ql[j][ks], a);
          a = mfma16(klf[ct][ks], qh[j][ks], a);
        }
        s[j][ct] = a;
      }

#pragma unroll
    for (int j = 0; j < 2; ++j) {
      // row max: 8 in-lane + 2 shuffles (kv axis = regs + 4 lane-groups)
      float mx = fmaxf(fmaxf(fmaxf(s[j][0][0], s[j][0][1]), fmaxf(s[j][0][2], s[j][0][3])),
                       fmaxf(fmaxf(s[j][1][0], s[j][1][1]), fmaxf(s[j][1][2], s[j][1][3])));
      mx = fmaxf(mx, __shfl_xor(mx, 16, 64));
      mx = fmaxf(mx, __shfl_xor(mx, 32, 64));
      const float mn = fmaxf(m_j[j], mx);
      const float sc = __expf(m_j[j] - mn);
      m_j[j] = mn;
      float rs = 0.f;
#pragma unroll
      for (int ct = 0; ct < 2; ++ct)
#pragma unroll
        for (int r = 0; r < 4; ++r) {
          const float e = __expf(s[j][ct][r] - mn);
          s[j][ct][r] = e;
          rs += e;
        }
      rs += __shfl_xor(rs, 16, 64);
      rs += __shfl_xor(rs, 32, 64);
      l_j[j] = l_j[j] * sc + rs;
#pragma unroll
      for (int co = 0; co < 4; ++co)
        acc[co][j] *= sc;

      // P (bf16 pairs) -> B-fragment of PV via 8 bpermutes + 4 selects (regs only)
      const u32 L0 = pk2(s[j][0][0], s[j][0][1]);
      const u32 H0 = pk2(s[j][0][2], s[j][0][3]);
      const u32 L1 = pk2(s[j][1][0], s[j][1][1]);
      const u32 H1 = pk2(s[j][1][2], s[j][1][3]);
      const u32 aL0 = (u32)__shfl((int)L0, sA, 64);
      const u32 aL1 = (u32)__shfl((int)L1, sA, 64);
      const u32 aH0 = (u32)__shfl((int)H0, sA, 64);
      const u32 aH1 = (u32)__shfl((int)H1, sA, 64);
      const u32 bL0 = (u32)__shfl((int)L0, sB, 64);
      const u32 bL1 = (u32)__shfl((int)L1, sB, 64);
      const u32 bH0 = (u32)__shfl((int)H0, sB, 64);
      const u32 bH1 = (u32)__shfl((int)H1, sB, 64);
      const u32x4 pw = (u32x4){hi_half ? aL1 : aL0,
                               hi_half ? aH1 : aH0,
                               hi_half ? bL1 : bL0,
                               hi_half ? bH1 : bH0};
      const bf16x8 pfv = __builtin_bit_cast(bf16x8, pw);
#pragma unroll
      for (int co = 0; co < 4; ++co)
        acc[co][j] = mfma16(vf[co], pfv, acc[co][j]);
    }

    // rotate pipeline registers (renamed by compiler, no real moves)
#pragma unroll
    for (int ct = 0; ct < 2; ++ct)
#pragma unroll
      for (int ks = 0; ks < 2; ++ks) {
        khf[ct][ks] = nkh[ct][ks];
        klf[ct][ks] = nkl[ct][ks];
      }
#pragma unroll
    for (int co = 0; co < 4; ++co)
      vf[co] = nvf[co];
  }

  // ---- flash-combine the 4 waves' partials in LDS ----
  float* ob = obuf + (size_t)(w * 64 + l) * 36;
#pragma unroll
  for (int co = 0; co < 4; ++co)
#pragma unroll
    for (int j = 0; j < 2; ++j)
      *(f32x4*)(ob + (co * 2 + j) * 4) = acc[co][j];
  if (g == 0) {
#pragma unroll
    for (int j = 0; j < 2; ++j) {
      mlbuf[((w * 2 + j) * 2 + 0) * 16 + c15] = m_j[j];
      mlbuf[((w * 2 + j) * 2 + 1) * 16 + c15] = l_j[j];
    }
  }
  __syncthreads();

  // wave w merges + writes channel tile co = w
  const float gm = gamma_p[0];
#pragma unroll
  for (int j = 0; j < 2; ++j) {
    float mw[4];
#pragma unroll
    for (int wp = 0; wp < 4; ++wp)
      mw[wp] = mlbuf[((wp * 2 + j) * 2 + 0) * 16 + c15];
    const float ms = fmaxf(fmaxf(mw[0], mw[1]), fmaxf(mw[2], mw[3]));
    float ls = 0.f;
    f32x4 mg = (f32x4){0.f, 0.f, 0.f, 0.f};
#pragma unroll
    for (int wp = 0; wp < 4; ++wp) {
      const float cf = __expf(mw[wp] - ms);
      ls += cf * mlbuf[((wp * 2 + j) * 2 + 1) * 16 + c15];
      const f32x4 pv = *(const f32x4*)(obuf + (size_t)(wp * 64 + l) * 36 + (w * 2 + j) * 4);
      mg += pv * cf;
    }
    const float inv = 1.0f / ls;
    const int q  = qt * QROWS + j * 16 + c15;
    const int cb = w * 16 + g * 4;
    const size_t base = ((size_t)(b * N_SZ + q)) * C_SZ + cb;
    const float4 iv = *(const float4*)(in + base);
    float4 ov;
    ov.x = gm * (mg[0] * inv) + iv.x;
    ov.y = gm * (mg[1] * inv) + iv.y;
    ov.z = gm * (mg[2] * inv) + iv.z;
    ov.w = gm * (mg[3] * inv) + iv.w;
    *(float4*)(out + base) = ov;
  }
}

extern "C" void kernel_launch(void* const* d_in, const int* in_sizes, int n_in,
                              void* d_out, int out_size, void* d_ws, size_t ws_size,
                              hipStream_t stream) {
  const float* in = (const float*)d_in[0];
  const float* gp = (const float*)d_in[1];
  float* op = (float*)d_out;
  const size_t plane = (size_t)B_SZ * N_SZ * C_SZ;   // 1.18M bf16 elems
  bf16_t* khi = (bf16_t*)d_ws;
  bf16_t* klo = khi + plane;
  bf16_t* vt  = klo + plane;                          // total 7.08 MB of ws
  hipLaunchKernelGGL(transform_k, dim3(288), dim3(256), 0, stream, in, khi, klo, vt);
  hipLaunchKernelGGL(attn_fwd, dim3(B_SZ * NQT), dim3(256), 0, stream,
                     in, khi, klo, vt, gp, op);
}

// Round 9
// 187.828 us; speedup vs baseline: 1.1122x; 1.1122x over previous
//
#include <hip/hip_runtime.h>

typedef __bf16 bf16_t;
typedef bf16_t bf16x8 __attribute__((ext_vector_type(8)));
typedef float  f32x4  __attribute__((ext_vector_type(4)));
typedef unsigned int u32;
typedef u32    u32x4  __attribute__((ext_vector_type(4)));
typedef unsigned short u16;

#define B_SZ   4
#define N_SZ   4608
#define C_SZ   64
#define KVB    32
#define QROWS  32
#define NKVT   (N_SZ / KVB)     // 144
#define NQT    (N_SZ / QROWS)   // 144
#define WV     4                // waves per attn block
#define SPLIT  4                // block-level KV split
#define TPC    (NKVT / SPLIT)   // 36 tiles per chunk
#define TPW    (TPC / WV)       // 9 tiles per wave
#define NBLK   (B_SZ * NQT * SPLIT)   // 2304 partial blocks
#define RSC    1.2011224087864498f    // sqrt(1/ln2): Q,K both scaled -> energy/ln2
#define THR    11.0f                  // defer-rescale threshold (base-2 units)

__device__ __forceinline__ f32x4 mfma16(bf16x8 a, bf16x8 b, f32x4 c) {
  return __builtin_amdgcn_mfma_f32_16x16x32_bf16(a, b, c, 0, 0, 0);
}

__device__ __forceinline__ u32 pk2(float a, float b) {
  u16 ua = __builtin_bit_cast(u16, (bf16_t)a);
  u16 ub = __builtin_bit_cast(u16, (bf16_t)b);
  return (u32)ua | ((u32)ub << 16);
}

// ---- pre-kernel: fp32 input -> khi/klo (bf16 hi/lo of RSC*v, row-major)
//                             -> vt (bf16 of v, transposed [b][c][n])
__global__ __launch_bounds__(256) void transform_k(
    const float* __restrict__ in, bf16_t* __restrict__ khi,
    bf16_t* __restrict__ klo, bf16_t* __restrict__ vt) {
  __shared__ float tile[64 * 65];
  const int bid = blockIdx.x;            // 288 blocks: (b, 64-row chunk)
  const int b  = bid / 72;
  const int n0 = (bid - b * 72) * 64;
  const int t  = threadIdx.x;
  {
    const int nl = t >> 2, c0 = (t & 3) * 16;
    const float* src = in + ((size_t)(b * N_SZ + n0 + nl)) * C_SZ + c0;
    float v[16];
    *(float4*)(v +  0) = *(const float4*)(src +  0);
    *(float4*)(v +  4) = *(const float4*)(src +  4);
    *(float4*)(v +  8) = *(const float4*)(src +  8);
    *(float4*)(v + 12) = *(const float4*)(src + 12);
    bf16x8 h8[2], l8[2];
#pragma unroll
    for (int i = 0; i < 16; ++i) {
      const float vs = RSC * v[i];
      bf16_t h = (bf16_t)vs;
      h8[i >> 3][i & 7] = h;
      l8[i >> 3][i & 7] = (bf16_t)(vs - (float)h);
      tile[nl * 65 + c0 + i] = v[i];     // vt stays UNSCALED
    }
    bf16_t* dh = khi + ((size_t)(b * N_SZ + n0 + nl)) * C_SZ + c0;
    bf16_t* dl = klo + ((size_t)(b * N_SZ + n0 + nl)) * C_SZ + c0;
    *(bf16x8*)(dh) = h8[0]; *(bf16x8*)(dh + 8) = h8[1];
    *(bf16x8*)(dl) = l8[0]; *(bf16x8*)(dl + 8) = l8[1];
  }
  __syncthreads();
  {
    const int c = t >> 2, m0 = (t & 3) * 16;
    bf16x8 o[2];
#pragma unroll
    for (int i = 0; i < 16; ++i)
      o[i >> 3][i & 7] = (bf16_t)tile[(m0 + i) * 65 + c];
    bf16_t* dst = vt + ((size_t)(b * C_SZ + c)) * N_SZ + n0 + m0;
    *(bf16x8*)(dst) = o[0]; *(bf16x8*)(dst + 8) = o[1];
  }
}

// load one KV tile's fragments (12 x dwordx4 global loads)
#define LOAD_TILE(KV0, KH, KL, VF)                                             \
  {                                                                            \
    _Pragma("unroll")                                                          \
    for (int ct = 0; ct < 2; ++ct)                                             \
      _Pragma("unroll")                                                        \
      for (int ks = 0; ks < 2; ++ks) {                                         \
        const size_t a = (size_t)((KV0) + ct * 16 + c15) * C_SZ + ks * 32 + g * 8; \
        KH[ct][ks] = *(const bf16x8*)(kh_b + a);                               \
        KL[ct][ks] = *(const bf16x8*)(kl_b + a);                               \
      }                                                                        \
    _Pragma("unroll")                                                          \
    for (int co = 0; co < 4; ++co)                                             \
      VF[co] = *(const bf16x8*)(vt_b + (size_t)(co * 16 + c15) * N_SZ + (KV0) + g * 8); \
  }

// ---- attention partials: 2304 blocks (b,qt,s) x 4 waves, 9 KV tiles/wave
__global__ __launch_bounds__(256, 2) void attn_part(
    const bf16_t* __restrict__ khi, const bf16_t* __restrict__ klo,
    const bf16_t* __restrict__ vt, float* __restrict__ wsO,
    float* __restrict__ wsML) {
  __shared__ float obuf[256 * 36];            // per-wave O^T partials
  __shared__ float mlbuf[4 * 2 * 2 * 16];     // [w][j][{m,l}][q16]

  const int bid0 = blockIdx.x;                      // 0..2303
  const int g8   = (bid0 & 7) * (NBLK / 8) + (bid0 >> 3);  // XCD-contiguous
  const int b    = g8 / (NQT * SPLIT);
  const int rem  = g8 - b * (NQT * SPLIT);
  const int s    = rem / NQT;
  const int qt   = rem - s * NQT;
  const int blk  = (b * NQT + qt) * SPLIT + s;      // partial index
  const int t  = threadIdx.x;
  const int w  = t >> 6, l = t & 63;
  const int c15 = l & 15, g = l >> 4;

  const bf16_t* kh_b = khi + (size_t)b * N_SZ * C_SZ;
  const bf16_t* kl_b = klo + (size_t)b * N_SZ * C_SZ;
  const bf16_t* vt_b = vt  + (size_t)b * C_SZ * N_SZ;

  // Q fragments (B-operand of swapped QK^T): B[k=ch][col=q-row]
  bf16x8 qh[2][2], ql[2][2];
#pragma unroll
  for (int j = 0; j < 2; ++j)
#pragma unroll
    for (int ks = 0; ks < 2; ++ks) {
      const size_t a = (size_t)(qt * QROWS + j * 16 + c15) * C_SZ + ks * 32 + g * 8;
      qh[j][ks] = *(const bf16x8*)(kh_b + a);
      ql[j][ks] = *(const bf16x8*)(kl_b + a);
    }

  f32x4 acc[4][2];   // O^T tiles: [c-tile][q-tile]
#pragma unroll
  for (int co = 0; co < 4; ++co)
#pragma unroll
    for (int j = 0; j < 2; ++j)
      acc[co][j] = (f32x4){0.f, 0.f, 0.f, 0.f};
  float m_j[2] = {-3.0e38f, -3.0e38f}, l_j[2] = {0.f, 0.f};

  const int sA = ((l >> 4) & 1) * 32 + c15;   // P-relayout source lanes
  const int sB = sA + 16;
  const bool hi_half = (l >= 32);

  // software pipeline: prefetch next tile's fragments
  bf16x8 khf[2][2], klf[2][2], vf[4];
  LOAD_TILE((s * TPC + w) * KVB, khf, klf, vf);

  for (int it = 0; it < TPW; ++it) {
    const int itn = (it + 1 < TPW) ? it + 1 : 0;
    const int kvn = (s * TPC + w + itn * WV) * KVB;
    bf16x8 nkh[2][2], nkl[2][2], nvf[4];
    LOAD_TILE(kvn, nkh, nkl, nvf);

    // S^T = K·Q^T (3-term hi/lo), base-2 energies
    f32x4 sv[2][2];
#pragma unroll
    for (int j = 0; j < 2; ++j)
#pragma unroll
      for (int ct = 0; ct < 2; ++ct) {
        f32x4 a = (f32x4){0.f, 0.f, 0.f, 0.f};
#pragma unroll
        for (int ks = 0; ks < 2; ++ks) {
          a = mfma16(khf[ct][ks], qh[j][ks], a);
          a = mfma16(khf[ct][ks], ql[j][ks], a);
          a = mfma16(klf[ct][ks], qh[j][ks], a);
        }
        sv[j][ct] = a;
      }

#pragma unroll
    for (int j = 0; j < 2; ++j) {
      float mx = fmaxf(fmaxf(fmaxf(sv[j][0][0], sv[j][0][1]), fmaxf(sv[j][0][2], sv[j][0][3])),
                       fmaxf(fmaxf(sv[j][1][0], sv[j][1][1]), fmaxf(sv[j][1][2], sv[j][1][3])));
      mx = fmaxf(mx, __shfl_xor(mx, 16, 64));
      mx = fmaxf(mx, __shfl_xor(mx, 32, 64));
      // T13 defer-rescale: only rescale when max grew by > THR (P <= 2^THR)
      if (__any(mx > m_j[j] + THR)) {
        const float mn = fmaxf(m_j[j], mx);
        const float sc = exp2f(m_j[j] - mn);
        m_j[j] = mn;
        l_j[j] *= sc;
#pragma unroll
        for (int co = 0; co < 4; ++co)
          acc[co][j] *= sc;
      }
      float rs = 0.f;
#pragma unroll
      for (int ct = 0; ct < 2; ++ct)
#pragma unroll
        for (int r = 0; r < 4; ++r) {
          const float e = exp2f(sv[j][ct][r] - m_j[j]);
          sv[j][ct][r] = e;
          rs += e;
        }
      rs += __shfl_xor(rs, 16, 64);
      rs += __shfl_xor(rs, 32, 64);
      l_j[j] += rs;

      // P (bf16 pairs) -> B-fragment of PV via 8 shuffles + selects (regs only)
      const u32 L0 = pk2(sv[j][0][0], sv[j][0][1]);
      const u32 H0 = pk2(sv[j][0][2], sv[j][0][3]);
      const u32 L1 = pk2(sv[j][1][0], sv[j][1][1]);
      const u32 H1 = pk2(sv[j][1][2], sv[j][1][3]);
      const u32 aL0 = (u32)__shfl((int)L0, sA, 64);
      const u32 aL1 = (u32)__shfl((int)L1, sA, 64);
      const u32 aH0 = (u32)__shfl((int)H0, sA, 64);
      const u32 aH1 = (u32)__shfl((int)H1, sA, 64);
      const u32 bL0 = (u32)__shfl((int)L0, sB, 64);
      const u32 bL1 = (u32)__shfl((int)L1, sB, 64);
      const u32 bH0 = (u32)__shfl((int)H0, sB, 64);
      const u32 bH1 = (u32)__shfl((int)H1, sB, 64);
      const u32x4 pw = (u32x4){hi_half ? aL1 : aL0,
                               hi_half ? aH1 : aH0,
                               hi_half ? bL1 : bL0,
                               hi_half ? bH1 : bH0};
      const bf16x8 pfv = __builtin_bit_cast(bf16x8, pw);
#pragma unroll
      for (int co = 0; co < 4; ++co)
        acc[co][j] = mfma16(vf[co], pfv, acc[co][j]);
    }

    // rotate pipeline registers
#pragma unroll
    for (int ct = 0; ct < 2; ++ct)
#pragma unroll
      for (int ks = 0; ks < 2; ++ks) {
        khf[ct][ks] = nkh[ct][ks];
        klf[ct][ks] = nkl[ct][ks];
      }
#pragma unroll
    for (int co = 0; co < 4; ++co)
      vf[co] = nvf[co];
  }

  // ---- flash-combine the 4 waves' partials; write chunk partial to ws ----
  float* ob = obuf + (size_t)(w * 64 + l) * 36;
#pragma unroll
  for (int co = 0; co < 4; ++co)
#pragma unroll
    for (int j = 0; j < 2; ++j)
      *(f32x4*)(ob + (co * 2 + j) * 4) = acc[co][j];
  if (g == 0) {
#pragma unroll
    for (int j = 0; j < 2; ++j) {
      mlbuf[((w * 2 + j) * 2 + 0) * 16 + c15] = m_j[j];
      mlbuf[((w * 2 + j) * 2 + 1) * 16 + c15] = l_j[j];
    }
  }
  __syncthreads();

  float* pO  = wsO  + (size_t)blk * (QROWS * C_SZ);
  float* pML = wsML + (size_t)blk * (QROWS * 2);
#pragma unroll
  for (int j = 0; j < 2; ++j) {
    float mw[4];
#pragma unroll
    for (int wp = 0; wp < 4; ++wp)
      mw[wp] = mlbuf[((wp * 2 + j) * 2 + 0) * 16 + c15];
    const float ms = fmaxf(fmaxf(mw[0], mw[1]), fmaxf(mw[2], mw[3]));
    float ls = 0.f;
    f32x4 mg = (f32x4){0.f, 0.f, 0.f, 0.f};
#pragma unroll
    for (int wp = 0; wp < 4; ++wp) {
      const float cf = exp2f(mw[wp] - ms);
      ls += cf * mlbuf[((wp * 2 + j) * 2 + 1) * 16 + c15];
      const f32x4 pv = *(const f32x4*)(obuf + (size_t)(wp * 64 + l) * 36 + (w * 2 + j) * 4);
      mg += pv * cf;
    }
    const int q  = j * 16 + c15;
    const int cb = w * 16 + g * 4;
    *(f32x4*)&pO[q * C_SZ + cb] = mg;         // un-normalized partial O
    if (w == 0 && g == 0) {
      pML[q * 2 + 0] = ms;
      pML[q * 2 + 1] = ls;
    }
  }
}

// ---- combine: 576 blocks (b,qt); merge 4 chunk-partials, residual+gamma ----
__global__ __launch_bounds__(256) void combine_k(
    const float* __restrict__ in, const float* __restrict__ gamma_p,
    const float* __restrict__ wsO, const float* __restrict__ wsML,
    float* __restrict__ out) {
  const int bid = blockIdx.x;            // b*NQT + qt
  const int b   = bid / NQT;
  const int qt  = bid - b * NQT;
  const int t   = threadIdx.x;
  const int q   = t >> 3;                // 0..31
  const int c0  = (t & 7) * 8;           // 0..56
  const int blk0 = bid * SPLIT;

  float m[SPLIT], lv[SPLIT];
  f32x4 o0[SPLIT], o1[SPLIT];
#pragma unroll
  for (int s = 0; s < SPLIT; ++s) {
    const float* pML = wsML + (size_t)(blk0 + s) * (QROWS * 2);
    m[s]  = pML[q * 2 + 0];
    lv[s] = pML[q * 2 + 1];
    const float* pO = wsO + (size_t)(blk0 + s) * (QROWS * C_SZ) + q * C_SZ + c0;
    o0[s] = *(const f32x4*)(pO);
    o1[s] = *(const f32x4*)(pO + 4);
  }
  const float ms = fmaxf(fmaxf(m[0], m[1]), fmaxf(m[2], m[3]));
  float ls = 0.f;
  f32x4 a0 = (f32x4){0.f, 0.f, 0.f, 0.f};
  f32x4 a1 = (f32x4){0.f, 0.f, 0.f, 0.f};
#pragma unroll
  for (int s = 0; s < SPLIT; ++s) {
    const float cf = exp2f(m[s] - ms);
    ls += cf * lv[s];
    a0 += o0[s] * cf;
    a1 += o1[s] * cf;
  }
  const float sc = gamma_p[0] / ls;
  const int row = qt * QROWS + q;
  const size_t base = ((size_t)(b * N_SZ + row)) * C_SZ + c0;
  const float4 i0 = *(const float4*)(in + base);
  const float4 i1 = *(const float4*)(in + base + 4);
  float4 v0, v1;
  v0.x = a0[0] * sc + i0.x; v0.y = a0[1] * sc + i0.y;
  v0.z = a0[2] * sc + i0.z; v0.w = a0[3] * sc + i0.w;
  v1.x = a1[0] * sc + i1.x; v1.y = a1[1] * sc + i1.y;
  v1.z = a1[2] * sc + i1.z; v1.w = a1[3] * sc + i1.w;
  *(float4*)(out + base)     = v0;
  *(float4*)(out + base + 4) = v1;
}

extern "C" void kernel_launch(void* const* d_in, const int* in_sizes, int n_in,
                              void* d_out, int out_size, void* d_ws, size_t ws_size,
                              hipStream_t stream) {
  const float* in = (const float*)d_in[0];
  const float* gp = (const float*)d_in[1];
  float* op = (float*)d_out;
  const size_t plane = (size_t)B_SZ * N_SZ * C_SZ;   // elements
  bf16_t* khi = (bf16_t*)d_ws;
  bf16_t* klo = khi + plane;
  bf16_t* vt  = klo + plane;
  float*  wsO  = (float*)((char*)d_ws + 3 * plane * sizeof(bf16_t));
  float*  wsML = wsO + (size_t)NBLK * (QROWS * C_SZ);
  // total ws use: 7.08 MB + 18.9 MB + 0.59 MB = 26.5 MB

  hipLaunchKernelGGL(transform_k, dim3(288), dim3(256), 0, stream, in, khi, klo, vt);
  hipLaunchKernelGGL(attn_part, dim3(NBLK), dim3(256), 0, stream,
                     khi, klo, vt, wsO, wsML);
  hipLaunchKernelGGL(combine_k, dim3(B_SZ * NQT), dim3(256), 0, stream,
                     in, gp, wsO, wsML, op);
}